// Round 1
// baseline (2259.312 us; speedup 1.0000x reference)
//
#include <hip/hip_runtime.h>
#include <hip/hip_bf16.h>

typedef unsigned short u16;
typedef short short8 __attribute__((ext_vector_type(8)));
typedef float f32x4 __attribute__((ext_vector_type(4)));

#define B_    32
#define N_    512
#define INF   1024
#define OUTF  4096
#define ROWS  16384     // B_*N_
#define HID_  128
#define CTRL  3072

__device__ __forceinline__ u16 f2bf(float f) {
    union { float fv; unsigned int u; } v; v.fv = f;
    unsigned int x = v.u;
    unsigned int r = (x + 0x7fffu + ((x >> 16) & 1u)) >> 16;
    return (u16)r;
}

// ---------------- stats (partial sums) + x->bf16 convert -------------------
__global__ __launch_bounds__(256) void k_stats(const float* __restrict__ x,
        u16* __restrict__ xb, float* __restrict__ ps, float* __restrict__ pq) {
    int b = blockIdx.y, bn = blockIdx.x, t = threadIdx.x;
    const float4* xp = (const float4*)(x + (size_t)b*(N_*INF) + (size_t)bn*64*INF);
    size_t obase = ((size_t)b*(N_*INF) + (size_t)bn*64*INF) >> 2;
    float sx=0, sy=0, sz=0, sw=0, qx=0, qy=0, qz=0, qw=0;
    for (int n = 0; n < 64; ++n) {
        float4 v = xp[n*256 + t];
        sx += v.x; sy += v.y; sz += v.z; sw += v.w;
        qx += v.x*v.x; qy += v.y*v.y; qz += v.z*v.z; qw += v.w*v.w;
        ushort4 o; o.x = f2bf(v.x); o.y = f2bf(v.y); o.z = f2bf(v.z); o.w = f2bf(v.w);
        ((ushort4*)xb)[obase + n*256 + t] = o;
    }
    int base = (b*8 + bn)*256 + t;   // float4 index into 32*8*1024 floats
    float4 s4; s4.x=sx; s4.y=sy; s4.z=sz; s4.w=sw;
    float4 q4; q4.x=qx; q4.y=qy; q4.z=qz; q4.w=qw;
    ((float4*)ps)[base] = s4;
    ((float4*)pq)[base] = q4;
}

// ---------------- control MLP: z -> h -> coeffs/gates ----------------------
__global__ __launch_bounds__(128) void k_ctrl(const float* __restrict__ x,
    const float* __restrict__ ps, const float* __restrict__ pq,
    const float* __restrict__ w1, const float* __restrict__ b1,
    const float* __restrict__ rcw, const float* __restrict__ rcb,
    const float* __restrict__ rgw, const float* __restrict__ rgb,
    const float* __restrict__ scw, const float* __restrict__ scb,
    const float* __restrict__ sgw, const float* __restrict__ sgb,
    float* __restrict__ rc, float* __restrict__ rg,
    float* __restrict__ sc, float* __restrict__ sg)
{
    __shared__ float zs[CTRL];
    __shared__ float hs[HID_];
    int b = blockIdx.x, t = threadIdx.x;
    for (int d = t; d < 1024; d += 128) {
        float ssum = 0.f, qsum = 0.f;
        for (int j = 0; j < 8; ++j) {
            ssum += ps[(b*8 + j)*1024 + d];
            qsum += pq[(b*8 + j)*1024 + d];
        }
        float mean = ssum * (1.0f/512.0f);
        float var  = qsum * (1.0f/512.0f) - mean*mean;
        zs[d]        = x[(size_t)b*(N_*INF) + d];  // cls token
        zs[1024 + d] = mean;
        zs[2048 + d] = var;
    }
    __syncthreads();
    float acc = b1[t];
    const float* wr = w1 + (size_t)t*CTRL;
    for (int i = 0; i < CTRL; ++i) acc += zs[i]*wr[i];
    float u = acc;
    float g = 0.5f*u*(1.0f + tanhf(0.7978845608028654f*(u + 0.044715f*u*u*u)));
    hs[t] = g;
    __syncthreads();
    if (t < 8) {
        float a = rcb[t]; const float* w = rcw + t*HID_;
        for (int i = 0; i < HID_; ++i) a += hs[i]*w[i];
        rc[b*8 + t] = a;
    } else if (t < 16) {
        int j = t - 8;
        float a = scb[j]; const float* w = scw + j*HID_;
        for (int i = 0; i < HID_; ++i) a += hs[i]*w[i];
        sc[b*8 + j] = a;
    } else if (t == 16) {
        float a = rgb[0] - 4.0f;   // ROT_GATE_BIAS
        for (int i = 0; i < HID_; ++i) a += hs[i]*rgw[i];
        rg[b] = 1.0f/(1.0f + expf(-a));
    } else if (t == 17) {
        float a = sgb[0] - 2.5f;   // SCALE_GATE_BIAS
        for (int i = 0; i < HID_; ++i) a += hs[i]*sgw[i];
        sg[b] = 1.0f/(1.0f + expf(-a));
    }
}

// ---------------- basis Frobenius norms via 8x8 Gram traces ----------------
// ||B - B^T||^2 = 2( tr((L^T L)(R^T R)) - tr((R^T L)^2) ),  B = L R^T
__global__ __launch_bounds__(64) void k_norms(const float* __restrict__ L,
        const float* __restrict__ R, float* __restrict__ norms) {
    int k = blockIdx.x, t = threadIdx.x;
    int i = t >> 3, j = t & 7;
    const float* Lk = L + ((size_t)k << 13);
    const float* Rk = R + ((size_t)k << 13);
    float aa = 0.f, cc = 0.f, dd = 0.f;
    for (int d = 0; d < 1024; ++d) {
        float li = Lk[(d<<3)+i], lj = Lk[(d<<3)+j];
        float ri = Rk[(d<<3)+i], rj = Rk[(d<<3)+j];
        aa += li*lj; cc += ri*rj; dd += ri*lj;   // D[i][j] = (R^T L)[i][j]
    }
    __shared__ float Ds[64];
    __shared__ float red[64];
    Ds[t] = dd;
    __syncthreads();
    float term = aa*cc - dd*Ds[(j<<3)+i];        // A_ij*C_ij - D_ij*D_ji
    red[t] = term;
    __syncthreads();
    for (int s2 = 32; s2 > 0; s2 >>= 1) {
        if (t < s2) red[t] += red[t+s2];
        __syncthreads();
    }
    if (t == 0) norms[k] = fmaxf(sqrtf(fmaxf(2.0f*red[0], 0.0f)), 1e-6f);
}

// ---------------- build U (1024x128 f32) and U^T (bf16, 128x1024) ----------
__global__ __launch_bounds__(256) void k_buildU(const float* __restrict__ L,
        const float* __restrict__ R, float* __restrict__ U, u16* __restrict__ Utb) {
    int idx = blockIdx.x*256 + threadIdx.x;    // 131072
    int d = idx >> 7, col = idx & 127;
    int k = col >> 4, rr = col & 15;
    float v = (rr < 8) ? L[((size_t)k<<13) + (d<<3) + rr]
                       : R[((size_t)k<<13) + (d<<3) + (rr-8)];
    U[idx] = v;
    Utb[col*1024 + d] = f2bf(v);
}

// ---------------- G = U^T U (128x128) --------------------------------------
__global__ __launch_bounds__(256) void k_gram(const float* __restrict__ U,
        float* __restrict__ G) {
    int e = blockIdx.x*256 + threadIdx.x;      // 16384
    int i = e >> 7, j = e & 127;
    float a = 0.f;
    for (int d = 0; d < 1024; ++d) a += U[d*128 + i]*U[d*128 + j];
    G[e] = a;
}

// ---------------- per-batch 128x128 inversion + P^T (bf16) -----------------
// A = I - 0.5*S*G, M = A^{-1}, Pt[j][i] = (g * M * S)[i][j] using S's 1-nonzero
// columns. LDS exactly 64 KB; rotate-by-row swizzle kills the 64-way conflict.
#define AS(r_, j_) As[(r_)][((j_) + (r_)) & 127]
__global__ __launch_bounds__(256) void k_solve(const float* __restrict__ G,
    const float* __restrict__ rc, const float* __restrict__ norms,
    const float* __restrict__ rg, u16* __restrict__ Ptb)
{
    __shared__ float As[128][128];
    int b = blockIdx.x, t = threadIdx.x;
    int r = t >> 1, j0 = (t & 1) << 6;
    int k = r >> 4, rr = r & 15;
    float ak = rc[b*8 + k] / norms[k];         // RESIDUAL_SCALE = 1
    {
        const float* Grow = (rr < 8) ? (G + (k*16 + 8 + rr)*128)
                                     : (G + (k*16 + rr - 8)*128);
        float s = (rr < 8) ? -0.5f*ak : 0.5f*ak;
        for (int jj = 0; jj < 64; ++jj) {
            int j = j0 + jj;
            float v = s * Grow[j];
            if (j == r) v += 1.0f;
            AS(r, j) = v;
        }
    }
    __syncthreads();
    for (int c = 0; c < 128; ++c) {
        float f = AS(r, c);                    // pre-scale column value (pivot if r==c)
        __syncthreads();
        if (r == c) {
            float ip = 1.0f / f;
            for (int jj = 0; jj < 64; ++jj) {
                int j = j0 + jj;
                AS(c, j) = (j == c) ? ip : AS(c, j) * ip;
            }
        }
        __syncthreads();
        if (r != c) {
            float fi = f * AS(c, c);           // AS(c,c) now holds 1/pivot
            for (int jj = 0; jj < 64; ++jj) {
                int j = j0 + jj;
                AS(r, j) = (j == c) ? -fi : AS(r, j) - fi * AS(c, j);
            }
        }
        __syncthreads();
    }
    float g = rg[b] * ak;                      // ADAPTER_SCALE = 1
    int col2 = (rr < 8) ? (k*16 + 8 + rr) : (k*16 + rr - 8);
    float sgn = (rr < 8) ? -g : g;
    for (int jj = 0; jj < 64; ++jj) {
        int i = j0 + jj;
        Ptb[((size_t)b*128 + r)*128 + i] = f2bf(sgn * AS(i, col2));
    }
}

// ---------------- output scale: 1 + sg*tanh(sc @ scale_basis) --------------
__global__ __launch_bounds__(256) void k_scale(const float* __restrict__ sc,
    const float* __restrict__ sbasis, const float* __restrict__ sg,
    float* __restrict__ scl) {
    int idx = blockIdx.x*256 + threadIdx.x;    // 131072
    int b = idx >> 12, o = idx & 4095;
    float a = 0.f;
    #pragma unroll
    for (int k = 0; k < 8; ++k) a += sc[b*8 + k]*sbasis[(k<<12) + o];
    scl[idx] = 1.0f + sg[b]*tanhf(a);
}

// ---------------- f32 -> bf16 bulk convert ---------------------------------
__global__ __launch_bounds__(256) void k_cvt(const float* __restrict__ in,
        u16* __restrict__ out, int n4) {
    int i = blockIdx.x*256 + threadIdx.x;
    if (i < n4) {
        float4 v = ((const float4*)in)[i];
        ushort4 o; o.x=f2bf(v.x); o.y=f2bf(v.y); o.z=f2bf(v.z); o.w=f2bf(v.w);
        ((ushort4*)out)[i] = o;
    }
}

// ---------------- generic bf16 MFMA GEMM: C[m,n] = sum_k A[m,k]*Bt[n,k] ----
// 128x128 tile, BK=64, 256 threads (4 waves, 2x2 of 64x64), bf16 out.
__global__ __launch_bounds__(256) void k_gemm_bt(const u16* __restrict__ A,
    const u16* __restrict__ Bt, u16* __restrict__ C,
    int M, int N, int K, long sA_, long sB_, long sC_)
{
    A  += (size_t)blockIdx.z * sA_;
    Bt += (size_t)blockIdx.z * sB_;
    C  += (size_t)blockIdx.z * sC_;
    int bm = blockIdx.y, bn = blockIdx.x;
    __shared__ __align__(16) u16 sA[128*64];
    __shared__ __align__(16) u16 sB[128*64];
    int tid = threadIdx.x;
    int wave = tid >> 6, lane = tid & 63;
    int wm = wave >> 1, wn = wave & 1;
    int quad = lane >> 4, l16 = lane & 15;
    f32x4 acc[4][4];
    #pragma unroll
    for (int i = 0; i < 4; ++i)
        #pragma unroll
        for (int j = 0; j < 4; ++j) { f32x4 z4 = {0.f,0.f,0.f,0.f}; acc[i][j] = z4; }
    int nk = K >> 6;
    for (int kt = 0; kt < nk; ++kt) {
        uint4 ra[4], rb[4];
        #pragma unroll
        for (int q2 = 0; q2 < 4; ++q2) {
            int c = q2*256 + tid, row = c >> 3, kc = c & 7;
            ra[q2] = *(const uint4*)(A  + (size_t)(bm*128 + row)*K + kt*64 + kc*8);
            rb[q2] = *(const uint4*)(Bt + (size_t)(bn*128 + row)*K + kt*64 + kc*8);
        }
        __syncthreads();
        #pragma unroll
        for (int q2 = 0; q2 < 4; ++q2) {
            ((uint4*)sA)[q2*256 + tid] = ra[q2];
            ((uint4*)sB)[q2*256 + tid] = rb[q2];
        }
        __syncthreads();
        #pragma unroll
        for (int ks = 0; ks < 2; ++ks) {
            short8 af[4], bfv[4];
            #pragma unroll
            for (int i = 0; i < 4; ++i)
                af[i] = *(const short8*)(sA + (wm*64 + i*16 + l16)*64 + ks*32 + quad*8);
            #pragma unroll
            for (int j = 0; j < 4; ++j)
                bfv[j] = *(const short8*)(sB + (wn*64 + j*16 + l16)*64 + ks*32 + quad*8);
            #pragma unroll
            for (int i = 0; i < 4; ++i)
                #pragma unroll
                for (int j = 0; j < 4; ++j)
                    acc[i][j] = __builtin_amdgcn_mfma_f32_16x16x32_bf16(af[i], bfv[j], acc[i][j], 0, 0, 0);
        }
    }
    #pragma unroll
    for (int i = 0; i < 4; ++i)
        #pragma unroll
        for (int j = 0; j < 4; ++j) {
            int gcol = bn*128 + wn*64 + j*16 + l16;
            #pragma unroll
            for (int r = 0; r < 4; ++r) {
                int grow = bm*128 + wm*64 + i*16 + quad*4 + r;
                C[(size_t)grow*N + gcol] = f2bf(acc[i][j][r]);
            }
        }
}

// ---------------- main fused GEMM: out = (x W^T + Q V^T + bias) * scale ----
__global__ __launch_bounds__(256) void k_main(const u16* __restrict__ xb,
    const u16* __restrict__ Wb, const u16* __restrict__ Qb,
    const u16* __restrict__ Vb, const float* __restrict__ bias,
    const float* __restrict__ scale, float* __restrict__ out)
{
    int bm = blockIdx.y, bn = blockIdx.x;
    __shared__ __align__(16) u16 sA[128*64];
    __shared__ __align__(16) u16 sB[128*64];
    int tid = threadIdx.x;
    int wave = tid >> 6, lane = tid & 63;
    int wm = wave >> 1, wn = wave & 1;
    int quad = lane >> 4, l16 = lane & 15;
    f32x4 acc[4][4];
    #pragma unroll
    for (int i = 0; i < 4; ++i)
        #pragma unroll
        for (int j = 0; j < 4; ++j) { f32x4 z4 = {0.f,0.f,0.f,0.f}; acc[i][j] = z4; }
    for (int kt = 0; kt < 18; ++kt) {
        uint4 ra[4], rb[4];
        if (kt < 16) {
            #pragma unroll
            for (int q2 = 0; q2 < 4; ++q2) {
                int c = q2*256 + tid, row = c >> 3, kc = c & 7;
                ra[q2] = *(const uint4*)(xb + (size_t)(bm*128 + row)*1024 + kt*64 + kc*8);
                rb[q2] = *(const uint4*)(Wb + (size_t)(bn*128 + row)*1024 + kt*64 + kc*8);
            }
        } else {
            int k0 = (kt - 16)*64;
            #pragma unroll
            for (int q2 = 0; q2 < 4; ++q2) {
                int c = q2*256 + tid, row = c >> 3, kc = c & 7;
                ra[q2] = *(const uint4*)(Qb + (size_t)(bm*128 + row)*128 + k0 + kc*8);
                rb[q2] = *(const uint4*)(Vb + (size_t)(bn*128 + row)*128 + k0 + kc*8);
            }
        }
        __syncthreads();
        #pragma unroll
        for (int q2 = 0; q2 < 4; ++q2) {
            ((uint4*)sA)[q2*256 + tid] = ra[q2];
            ((uint4*)sB)[q2*256 + tid] = rb[q2];
        }
        __syncthreads();
        #pragma unroll
        for (int ks = 0; ks < 2; ++ks) {
            short8 af[4], bfv[4];
            #pragma unroll
            for (int i = 0; i < 4; ++i)
                af[i] = *(const short8*)(sA + (wm*64 + i*16 + l16)*64 + ks*32 + quad*8);
            #pragma unroll
            for (int j = 0; j < 4; ++j)
                bfv[j] = *(const short8*)(sB + (wn*64 + j*16 + l16)*64 + ks*32 + quad*8);
            #pragma unroll
            for (int i = 0; i < 4; ++i)
                #pragma unroll
                for (int j = 0; j < 4; ++j)
                    acc[i][j] = __builtin_amdgcn_mfma_f32_16x16x32_bf16(af[i], bfv[j], acc[i][j], 0, 0, 0);
        }
    }
    const float* scrow = scale + (bm >> 2)*4096;  // 128-row blocks never cross batch
    #pragma unroll
    for (int i = 0; i < 4; ++i)
        #pragma unroll
        for (int j = 0; j < 4; ++j) {
            int gcol = bn*128 + wn*64 + j*16 + l16;
            float bc = bias[gcol];
            float sv = scrow[gcol];
            #pragma unroll
            for (int r = 0; r < 4; ++r) {
                int grow = bm*128 + wm*64 + i*16 + quad*4 + r;
                out[(size_t)grow*4096 + gcol] = (acc[i][j][r] + bc) * sv;
            }
        }
}

extern "C" void kernel_launch(void* const* d_in, const int* in_sizes, int n_in,
                              void* d_out, int out_size, void* d_ws, size_t ws_size,
                              hipStream_t stream)
{
    const float* x     = (const float*)d_in[0];
    const float* Wsh   = (const float*)d_in[1];
    const float* bias  = (const float*)d_in[2];
    const float* left  = (const float*)d_in[3];
    const float* right = (const float*)d_in[4];
    const float* sbasis= (const float*)d_in[5];
    const float* w1    = (const float*)d_in[6];
    const float* b1    = (const float*)d_in[7];
    const float* rcw   = (const float*)d_in[8];
    const float* rcb   = (const float*)d_in[9];
    const float* rgw   = (const float*)d_in[10];
    const float* rgb   = (const float*)d_in[11];
    const float* scw   = (const float*)d_in[12];
    const float* scb   = (const float*)d_in[13];
    const float* sgw   = (const float*)d_in[14];
    const float* sgb   = (const float*)d_in[15];
    float* out = (float*)d_out;
    (void)in_sizes; (void)n_in; (void)out_size; (void)ws_size;

    char* wsp = (char*)d_ws;
    size_t off = 0;
    auto take = [&](size_t bytes) -> char* {
        char* p = wsp + off;
        off = (off + bytes + 255) & ~(size_t)255;
        return p;
    };
    u16*   xb   = (u16*)  take((size_t)ROWS*INF*2);     // 32 MB
    u16*   Wb   = (u16*)  take((size_t)OUTF*INF*2);     // 8 MB
    u16*   Utb  = (u16*)  take((size_t)128*1024*2);
    u16*   Yb   = (u16*)  take((size_t)ROWS*128*2);     // 4 MB
    u16*   Qb   = (u16*)  take((size_t)ROWS*128*2);     // 4 MB
    u16*   Vb   = (u16*)  take((size_t)OUTF*128*2);     // 1 MB
    u16*   Ptb  = (u16*)  take((size_t)32*128*128*2);   // 1 MB
    float* Uf   = (float*)take((size_t)1024*128*4);
    float* Gf   = (float*)take((size_t)128*128*4);
    float* ps   = (float*)take((size_t)32*8*1024*4);
    float* pq   = (float*)take((size_t)32*8*1024*4);
    float* rc   = (float*)take(32*8*4);
    float* sc   = (float*)take(32*8*4);
    float* rg   = (float*)take(32*4);
    float* sg   = (float*)take(32*4);
    float* nrm  = (float*)take(8*4);
    float* scl  = (float*)take((size_t)32*4096*4);

    k_cvt   <<<dim3(4096),   dim3(256), 0, stream>>>(Wsh, Wb, OUTF*INF/4);
    k_stats <<<dim3(8,32),   dim3(256), 0, stream>>>(x, xb, ps, pq);
    k_ctrl  <<<dim3(32),     dim3(128), 0, stream>>>(x, ps, pq, w1, b1, rcw, rcb,
                                                     rgw, rgb, scw, scb, sgw, sgb,
                                                     rc, rg, sc, sg);
    k_norms <<<dim3(8),      dim3(64),  0, stream>>>(left, right, nrm);
    k_buildU<<<dim3(512),    dim3(256), 0, stream>>>(left, right, Uf, Utb);
    k_gram  <<<dim3(64),     dim3(256), 0, stream>>>(Uf, Gf);
    k_solve <<<dim3(32),     dim3(256), 0, stream>>>(Gf, rc, nrm, rg, Ptb);
    k_scale <<<dim3(512),    dim3(256), 0, stream>>>(sc, sbasis, sg, scl);
    // Y = x U            (16384 x 128, K=1024)
    k_gemm_bt<<<dim3(1,128,1), dim3(256), 0, stream>>>(xb, Utb, Yb, ROWS, 128, 1024, 0L, 0L, 0L);
    // Q = Y P  per batch (512 x 128, K=128)
    k_gemm_bt<<<dim3(1,4,32),  dim3(256), 0, stream>>>(Yb, Ptb, Qb, 512, 128, 128,
                                                       (long)512*128, (long)128*128, (long)512*128);
    // V = Wsh U          (4096 x 128, K=1024)
    k_gemm_bt<<<dim3(1,32,1),  dim3(256), 0, stream>>>(Wb, Utb, Vb, OUTF, 128, 1024, 0L, 0L, 0L);
    // out = (x W^T + Q V^T + bias) * scale
    k_main  <<<dim3(32,128), dim3(256), 0, stream>>>(xb, Wb, Qb, Vb, bias, scl, out);
}

// Round 2
// 1341.065 us; speedup vs baseline: 1.6847x; 1.6847x over previous
//
#include <hip/hip_runtime.h>
#include <hip/hip_bf16.h>

typedef unsigned short u16;
typedef short short8 __attribute__((ext_vector_type(8)));
typedef float f32x4 __attribute__((ext_vector_type(4)));

#define B_    32
#define N_    512
#define INF   1024
#define OUTF  4096
#define ROWS  16384     // B_*N_
#define HID_  128
#define CTRL  3072

__device__ __forceinline__ u16 f2bf(float f) {
    union { float fv; unsigned int u; } v; v.fv = f;
    unsigned int x = v.u;
    unsigned int r = (x + 0x7fffu + ((x >> 16) & 1u)) >> 16;
    return (u16)r;
}

// async global->LDS, 16B per lane. lds ptr must be the WAVE-UNIFORM base;
// lane l deposits at base + l*16. AS casts via inttoptr (LDS generic addr
// low 32 bits == LDS offset on gfx9+).
__device__ __forceinline__ void gll16(const void* g, const void* l) {
    __builtin_amdgcn_global_load_lds(
        (__attribute__((address_space(1))) void*)(unsigned long long)g,
        (__attribute__((address_space(3))) void*)(unsigned int)(unsigned long long)l,
        16, 0, 0);
}

__device__ __forceinline__ float sel16f(const float4 o[4], int m) {
    float v = o[0].x;
    v = (m == 1) ? o[0].y : v;  v = (m == 2) ? o[0].z : v;  v = (m == 3) ? o[0].w : v;
    v = (m == 4) ? o[1].x : v;  v = (m == 5) ? o[1].y : v;  v = (m == 6) ? o[1].z : v;  v = (m == 7) ? o[1].w : v;
    v = (m == 8) ? o[2].x : v;  v = (m == 9) ? o[2].y : v;  v = (m == 10) ? o[2].z : v; v = (m == 11) ? o[2].w : v;
    v = (m == 12) ? o[3].x : v; v = (m == 13) ? o[3].y : v; v = (m == 14) ? o[3].z : v; v = (m == 15) ? o[3].w : v;
    return v;
}

// ---------------- stats (partial sums) + x->bf16 convert -------------------
__global__ __launch_bounds__(256) void k_stats(const float* __restrict__ x,
        u16* __restrict__ xb, float* __restrict__ ps, float* __restrict__ pq) {
    int b = blockIdx.y, bn = blockIdx.x, t = threadIdx.x;
    const float4* xp = (const float4*)(x + (size_t)b*(N_*INF) + (size_t)bn*64*INF);
    size_t obase = ((size_t)b*(N_*INF) + (size_t)bn*64*INF) >> 2;
    float sx=0, sy=0, sz=0, sw=0, qx=0, qy=0, qz=0, qw=0;
    for (int n = 0; n < 64; ++n) {
        float4 v = xp[n*256 + t];
        sx += v.x; sy += v.y; sz += v.z; sw += v.w;
        qx += v.x*v.x; qy += v.y*v.y; qz += v.z*v.z; qw += v.w*v.w;
        ushort4 o; o.x = f2bf(v.x); o.y = f2bf(v.y); o.z = f2bf(v.z); o.w = f2bf(v.w);
        ((ushort4*)xb)[obase + n*256 + t] = o;
    }
    int base = (b*8 + bn)*256 + t;
    float4 s4; s4.x=sx; s4.y=sy; s4.z=sz; s4.w=sw;
    float4 q4; q4.x=qx; q4.y=qy; q4.z=qz; q4.w=qw;
    ((float4*)ps)[base] = s4;
    ((float4*)pq)[base] = q4;
}

// ---------------- control MLP: coalesced wave-per-row GEMV -----------------
__global__ __launch_bounds__(256) void k_ctrl(const float* __restrict__ x,
    const float* __restrict__ ps, const float* __restrict__ pq,
    const float* __restrict__ w1, const float* __restrict__ b1,
    const float* __restrict__ rcw, const float* __restrict__ rcb,
    const float* __restrict__ rgw, const float* __restrict__ rgb,
    const float* __restrict__ scw, const float* __restrict__ scb,
    const float* __restrict__ sgw, const float* __restrict__ sgb,
    float* __restrict__ rc, float* __restrict__ rg,
    float* __restrict__ sc, float* __restrict__ sg)
{
    __shared__ float zs[CTRL];
    __shared__ float hs[HID_];
    int b = blockIdx.x, t = threadIdx.x;
    for (int d = t; d < 1024; d += 256) {
        float ssum = 0.f, qsum = 0.f;
        for (int j = 0; j < 8; ++j) {
            ssum += ps[(b*8 + j)*1024 + d];
            qsum += pq[(b*8 + j)*1024 + d];
        }
        float mean = ssum * (1.0f/512.0f);
        float var  = qsum * (1.0f/512.0f) - mean*mean;
        zs[d]        = x[(size_t)b*(N_*INF) + d];
        zs[1024 + d] = mean;
        zs[2048 + d] = var;
    }
    __syncthreads();
    int w = t >> 6, l = t & 63;
    const float4* zp = (const float4*)zs;
    for (int i = w; i < HID_; i += 4) {
        const float4* wr = (const float4*)(w1 + (size_t)i*CTRL);
        float acc = 0.f;
        #pragma unroll
        for (int c = 0; c < 12; ++c) {
            float4 a4 = wr[l + 64*c];
            float4 z4 = zp[l + 64*c];
            acc += a4.x*z4.x + a4.y*z4.y + a4.z*z4.z + a4.w*z4.w;
        }
        #pragma unroll
        for (int o2 = 32; o2 > 0; o2 >>= 1) acc += __shfl_down(acc, o2, 64);
        if (l == 0) {
            float u = acc + b1[i];
            hs[i] = 0.5f*u*(1.0f + tanhf(0.7978845608028654f*(u + 0.044715f*u*u*u)));
        }
    }
    __syncthreads();
    if (t < 8) {
        float a = rcb[t]; const float* wv = rcw + t*HID_;
        for (int i = 0; i < HID_; ++i) a += hs[i]*wv[i];
        rc[b*8 + t] = a;
    } else if (t < 16) {
        int j = t - 8;
        float a = scb[j]; const float* wv = scw + j*HID_;
        for (int i = 0; i < HID_; ++i) a += hs[i]*wv[i];
        sc[b*8 + j] = a;
    } else if (t == 16) {
        float a = rgb[0] - 4.0f;
        for (int i = 0; i < HID_; ++i) a += hs[i]*rgw[i];
        rg[b] = 1.0f/(1.0f + expf(-a));
    } else if (t == 17) {
        float a = sgb[0] - 2.5f;
        for (int i = 0; i < HID_; ++i) a += hs[i]*sgw[i];
        sg[b] = 1.0f/(1.0f + expf(-a));
    }
}

// ---------------- basis norms from Gram blocks of G ------------------------
// ||B-B^T||^2 = 2( sum_ij A_ij*C_ij - D_ij*D_ji ), A=L^TL, C=R^TR, D=R^TL
__global__ __launch_bounds__(64) void k_norms(const float* __restrict__ G,
        float* __restrict__ norms) {
    int k = blockIdx.x, t = threadIdx.x;
    int i = t >> 3, j = t & 7;
    float A  = G[(16*k + i)*128     + 16*k + j];
    float C  = G[(16*k + 8 + i)*128 + 16*k + 8 + j];
    float D  = G[(16*k + 8 + i)*128 + 16*k + j];
    float Dj = G[(16*k + 8 + j)*128 + 16*k + i];
    float term = A*C - D*Dj;
    #pragma unroll
    for (int o2 = 32; o2 > 0; o2 >>= 1) term += __shfl_down(term, o2, 64);
    if (t == 0) norms[k] = fmaxf(sqrtf(fmaxf(2.0f*term, 0.0f)), 1e-6f);
}

// ---------------- build U (1024x128 f32) and U^T (bf16, 128x1024) ----------
__global__ __launch_bounds__(256) void k_buildU(const float* __restrict__ L,
        const float* __restrict__ R, float* __restrict__ U, u16* __restrict__ Utb) {
    int idx = blockIdx.x*256 + threadIdx.x;
    int d = idx >> 7, col = idx & 127;
    int k = col >> 4, rr = col & 15;
    float v = (rr < 8) ? L[((size_t)k<<13) + (d<<3) + rr]
                       : R[((size_t)k<<13) + (d<<3) + (rr-8)];
    U[idx] = v;
    Utb[col*1024 + d] = f2bf(v);
}

// ---------------- G = U^T U (128x128) --------------------------------------
__global__ __launch_bounds__(256) void k_gram(const float* __restrict__ U,
        float* __restrict__ G) {
    int e = blockIdx.x*256 + threadIdx.x;
    int i = e >> 7, j = e & 127;
    float a = 0.f;
    for (int d = 0; d < 1024; ++d) a += U[d*128 + i]*U[d*128 + j];
    G[e] = a;
}

// ---------------- per-batch 128x128 inversion, register-resident GJ --------
// A = I - 0.5*S*G held in VGPRs: thread (r=t&127, s=t>>7) owns A[r][16s..16s+15].
// LDS: double-buffered pivot row (with +1 marker at the pivot column so the
// j==c fix falls out of the fma) and pivot column. 1 barrier per column.
// Epilogue writes Pt[j][i] = g*(M*S)[i][j] (bf16) via an LDS transpose.
__global__ __launch_bounds__(1024) void k_solve(const float* __restrict__ G,
    const float* __restrict__ rc, const float* __restrict__ norms,
    const float* __restrict__ rg, u16* __restrict__ Ptb)
{
    __shared__ float smem[16384];          // 64KB; first 512 floats = pivot bufs
    float* prow = smem;                    // [2][128]
    float* pcol = smem + 256;              // [2][128]
    int b = blockIdx.x, t = threadIdx.x;
    int r = t & 127, s = t >> 7;           // s is wave-uniform
    int kr = r >> 4, rr = r & 15;
    float a_r = rc[b*8 + kr] / norms[kr];
    int partner = (rr < 8) ? (kr*16 + 8 + rr) : (kr*16 + rr - 8);
    float sg0 = (rr < 8) ? -0.5f*a_r : 0.5f*a_r;
    float4 o[4];
    {
        const float4* Gp = (const float4*)(G + (size_t)partner*128 + 16*s);
        #pragma unroll
        for (int q = 0; q < 4; ++q) {
            float4 g4 = Gp[q];
            int base = 16*s + 4*q;
            o[q].x = sg0*g4.x + ((r == base)     ? 1.f : 0.f);
            o[q].y = sg0*g4.y + ((r == base + 1) ? 1.f : 0.f);
            o[q].z = sg0*g4.z + ((r == base + 2) ? 1.f : 0.f);
            o[q].w = sg0*g4.w + ((r == base + 3) ? 1.f : 0.f);
        }
    }
    // pivots for column 0 -> buffer 0 (marker +1 at element j==0)
    if (r == 0) {
        #pragma unroll
        for (int q = 0; q < 4; ++q) {
            float4 v = o[q];
            if (s == 0 && q == 0) v.x += 1.0f;
            *(float4*)(prow + 16*s + 4*q) = v;
        }
    }
    if (s == 0) pcol[r] = sel16f(o, 0);
    __syncthreads();
    for (int c = 0; c < 128; ++c) {
        int buf = c & 1, nb = buf ^ 1;
        float fr = pcol[buf*128 + r];
        const float4* prp = (const float4*)(prow + buf*128 + 16*s);
        float4 p0 = prp[0], p1 = prp[1], p2 = prp[2], p3 = prp[3];
        float pv = prow[buf*128 + c] - 1.0f;   // un-marked pivot value
        float invp = 1.0f / pv;
        if (r == c) {
            #pragma unroll
            for (int q = 0; q < 4; ++q) {
                int base = 16*s + 4*q;
                o[q].x = (base     == c) ? invp : o[q].x*invp;
                o[q].y = (base + 1 == c) ? invp : o[q].y*invp;
                o[q].z = (base + 2 == c) ? invp : o[q].z*invp;
                o[q].w = (base + 3 == c) ? invp : o[q].w*invp;
            }
        } else {
            float fi = fr * invp;
            o[0].x -= fi*p0.x; o[0].y -= fi*p0.y; o[0].z -= fi*p0.z; o[0].w -= fi*p0.w;
            o[1].x -= fi*p1.x; o[1].y -= fi*p1.y; o[1].z -= fi*p1.z; o[1].w -= fi*p1.w;
            o[2].x -= fi*p2.x; o[2].y -= fi*p2.y; o[2].z -= fi*p2.z; o[2].w -= fi*p2.w;
            o[3].x -= fi*p3.x; o[3].y -= fi*p3.y; o[3].z -= fi*p3.z; o[3].w -= fi*p3.w;
        }
        int cn = c + 1;
        if (cn < 128) {
            if (r == cn) {
                #pragma unroll
                for (int q = 0; q < 4; ++q) {
                    float4 v = o[q];
                    int base = 16*s + 4*q;
                    v.x += (base     == cn) ? 1.f : 0.f;
                    v.y += (base + 1 == cn) ? 1.f : 0.f;
                    v.z += (base + 2 == cn) ? 1.f : 0.f;
                    v.w += (base + 3 == cn) ? 1.f : 0.f;
                    *(float4*)(prow + nb*128 + 16*s + 4*q) = v;
                }
            }
            if (s == (cn >> 4)) pcol[nb*128 + r] = sel16f(o, cn & 15);
        }
        __syncthreads();
    }
    // epilogue: ms = g * (M*S)[r][16s..16s+15]; Pt[16s+m][r] = ms[m]
    float as_ = rc[b*8 + s] / norms[s];
    float gg = rg[b];
    float na = -gg * as_, pa = gg * as_;
    float msv[16];
    msv[0] = na*o[2].x; msv[1] = na*o[2].y; msv[2]  = na*o[2].z; msv[3]  = na*o[2].w;
    msv[4] = na*o[3].x; msv[5] = na*o[3].y; msv[6]  = na*o[3].z; msv[7]  = na*o[3].w;
    msv[8] = pa*o[0].x; msv[9] = pa*o[0].y; msv[10] = pa*o[0].z; msv[11] = pa*o[0].w;
    msv[12]= pa*o[1].x; msv[13]= pa*o[1].y; msv[14] = pa*o[1].z; msv[15] = pa*o[1].w;
    #pragma unroll
    for (int m = 0; m < 16; ++m)
        smem[(16*s + m)*128 + r] = msv[m];
    __syncthreads();
    int r2 = t >> 3, s2 = t & 7;
    const float4* rp = (const float4*)(smem + r2*128 + 16*s2);
    float4 v0 = rp[0], v1 = rp[1], v2 = rp[2], v3 = rp[3];
    uint4 w0, w1;
    w0.x = f2bf(v0.x) | ((unsigned)f2bf(v0.y) << 16);
    w0.y = f2bf(v0.z) | ((unsigned)f2bf(v0.w) << 16);
    w0.z = f2bf(v1.x) | ((unsigned)f2bf(v1.y) << 16);
    w0.w = f2bf(v1.z) | ((unsigned)f2bf(v1.w) << 16);
    w1.x = f2bf(v2.x) | ((unsigned)f2bf(v2.y) << 16);
    w1.y = f2bf(v2.z) | ((unsigned)f2bf(v2.w) << 16);
    w1.z = f2bf(v3.x) | ((unsigned)f2bf(v3.y) << 16);
    w1.w = f2bf(v3.z) | ((unsigned)f2bf(v3.w) << 16);
    uint4* dst = (uint4*)(Ptb + ((size_t)(b*128 + r2))*128 + 16*s2);
    dst[0] = w0; dst[1] = w1;
}

// ---------------- output scale: 1 + sg*tanh(sc @ scale_basis) --------------
__global__ __launch_bounds__(256) void k_scale(const float* __restrict__ sc,
    const float* __restrict__ sbasis, const float* __restrict__ sg,
    float* __restrict__ scl) {
    int idx = blockIdx.x*256 + threadIdx.x;
    int b = idx >> 12, o = idx & 4095;
    float a = 0.f;
    #pragma unroll
    for (int k = 0; k < 8; ++k) a += sc[b*8 + k]*sbasis[(k<<12) + o];
    scl[idx] = 1.0f + sg[b]*tanhf(a);
}

// ---------------- f32 -> bf16 bulk convert ---------------------------------
__global__ __launch_bounds__(256) void k_cvt(const float* __restrict__ in,
        u16* __restrict__ out, int n4) {
    int i = blockIdx.x*256 + threadIdx.x;
    if (i < n4) {
        float4 v = ((const float4*)in)[i];
        ushort4 o; o.x=f2bf(v.x); o.y=f2bf(v.y); o.z=f2bf(v.z); o.w=f2bf(v.w);
        ((ushort4*)out)[i] = o;
    }
}

// ---------------- generic bf16 MFMA GEMM: C[m,n] = sum_k A[m,k]*Bt[n,k] ----
__global__ __launch_bounds__(256) void k_gemm_bt(const u16* __restrict__ A,
    const u16* __restrict__ Bt, u16* __restrict__ C,
    int M, int N, int K, long sA_, long sB_, long sC_)
{
    A  += (size_t)blockIdx.z * sA_;
    Bt += (size_t)blockIdx.z * sB_;
    C  += (size_t)blockIdx.z * sC_;
    int bm = blockIdx.y, bn = blockIdx.x;
    __shared__ __align__(16) u16 sA[128*64];
    __shared__ __align__(16) u16 sB[128*64];
    int tid = threadIdx.x;
    int wave = tid >> 6, lane = tid & 63;
    int wbase = tid & ~63;
    int wm = wave >> 1, wn = wave & 1;
    int quad = lane >> 4, l16 = lane & 15;
    f32x4 acc[4][4];
    #pragma unroll
    for (int i = 0; i < 4; ++i)
        #pragma unroll
        for (int j = 0; j < 4; ++j) { f32x4 z4 = {0.f,0.f,0.f,0.f}; acc[i][j] = z4; }
    int nk = K >> 6;
    for (int kt = 0; kt < nk; ++kt) {
        __syncthreads();
        #pragma unroll
        for (int q2 = 0; q2 < 4; ++q2) {
            int c = q2*256 + tid, row = c >> 3, kc = c & 7;
            gll16(A  + (size_t)(bm*128 + row)*K + kt*64 + kc*8, sA + (size_t)(q2*256 + wbase)*8);
            gll16(Bt + (size_t)(bn*128 + row)*K + kt*64 + kc*8, sB + (size_t)(q2*256 + wbase)*8);
        }
        __syncthreads();
        #pragma unroll
        for (int ks = 0; ks < 2; ++ks) {
            short8 af[4], bfv[4];
            #pragma unroll
            for (int i = 0; i < 4; ++i)
                af[i] = *(const short8*)(sA + (wm*64 + i*16 + l16)*64 + ks*32 + quad*8);
            #pragma unroll
            for (int j = 0; j < 4; ++j)
                bfv[j] = *(const short8*)(sB + (wn*64 + j*16 + l16)*64 + ks*32 + quad*8);
            #pragma unroll
            for (int i = 0; i < 4; ++i)
                #pragma unroll
                for (int j = 0; j < 4; ++j)
                    acc[i][j] = __builtin_amdgcn_mfma_f32_16x16x32_bf16(af[i], bfv[j], acc[i][j], 0, 0, 0);
        }
    }
    #pragma unroll
    for (int i = 0; i < 4; ++i)
        #pragma unroll
        for (int j = 0; j < 4; ++j) {
            int gcol = bn*128 + wn*64 + j*16 + l16;
            #pragma unroll
            for (int r = 0; r < 4; ++r) {
                int grow = bm*128 + wm*64 + i*16 + quad*4 + r;
                C[(size_t)grow*N + gcol] = f2bf(acc[i][j][r]);
            }
        }
}

// ---------------- main fused GEMM: out = (x W^T + Q V^T + bias) * scale ----
__global__ __launch_bounds__(256) void k_main(const u16* __restrict__ xb,
    const u16* __restrict__ Wb, const u16* __restrict__ Qb,
    const u16* __restrict__ Vb, const float* __restrict__ bias,
    const float* __restrict__ scale, float* __restrict__ out)
{
    int bm = blockIdx.y, bn = blockIdx.x;
    __shared__ __align__(16) u16 sA[128*64];
    __shared__ __align__(16) u16 sB[128*64];
    int tid = threadIdx.x;
    int wave = tid >> 6, lane = tid & 63;
    int wbase = tid & ~63;
    int wm = wave >> 1, wn = wave & 1;
    int quad = lane >> 4, l16 = lane & 15;
    f32x4 acc[4][4];
    #pragma unroll
    for (int i = 0; i < 4; ++i)
        #pragma unroll
        for (int j = 0; j < 4; ++j) { f32x4 z4 = {0.f,0.f,0.f,0.f}; acc[i][j] = z4; }
    for (int kt = 0; kt < 18; ++kt) {
        __syncthreads();
        if (kt < 16) {
            #pragma unroll
            for (int q2 = 0; q2 < 4; ++q2) {
                int c = q2*256 + tid, row = c >> 3, kc = c & 7;
                gll16(xb + (size_t)(bm*128 + row)*1024 + kt*64 + kc*8, sA + (size_t)(q2*256 + wbase)*8);
                gll16(Wb + (size_t)(bn*128 + row)*1024 + kt*64 + kc*8, sB + (size_t)(q2*256 + wbase)*8);
            }
        } else {
            int k0 = (kt - 16)*64;
            #pragma unroll
            for (int q2 = 0; q2 < 4; ++q2) {
                int c = q2*256 + tid, row = c >> 3, kc = c & 7;
                gll16(Qb + (size_t)(bm*128 + row)*128 + k0 + kc*8, sA + (size_t)(q2*256 + wbase)*8);
                gll16(Vb + (size_t)(bn*128 + row)*128 + k0 + kc*8, sB + (size_t)(q2*256 + wbase)*8);
            }
        }
        __syncthreads();
        #pragma unroll
        for (int ks = 0; ks < 2; ++ks) {
            short8 af[4], bfv[4];
            #pragma unroll
            for (int i = 0; i < 4; ++i)
                af[i] = *(const short8*)(sA + (wm*64 + i*16 + l16)*64 + ks*32 + quad*8);
            #pragma unroll
            for (int j = 0; j < 4; ++j)
                bfv[j] = *(const short8*)(sB + (wn*64 + j*16 + l16)*64 + ks*32 + quad*8);
            #pragma unroll
            for (int i = 0; i < 4; ++i)
                #pragma unroll
                for (int j = 0; j < 4; ++j)
                    acc[i][j] = __builtin_amdgcn_mfma_f32_16x16x32_bf16(af[i], bfv[j], acc[i][j], 0, 0, 0);
        }
    }
    const float* scrow = scale + (bm >> 2)*4096;  // 128-row blocks never cross batch
    #pragma unroll
    for (int i = 0; i < 4; ++i)
        #pragma unroll
        for (int j = 0; j < 4; ++j) {
            int gcol = bn*128 + wn*64 + j*16 + l16;
            float bc = bias[gcol];
            float sv = scrow[gcol];
            #pragma unroll
            for (int r = 0; r < 4; ++r) {
                int grow = bm*128 + wm*64 + i*16 + quad*4 + r;
                out[(size_t)grow*4096 + gcol] = (acc[i][j][r] + bc) * sv;
            }
        }
}

extern "C" void kernel_launch(void* const* d_in, const int* in_sizes, int n_in,
                              void* d_out, int out_size, void* d_ws, size_t ws_size,
                              hipStream_t stream)
{
    const float* x     = (const float*)d_in[0];
    const float* Wsh   = (const float*)d_in[1];
    const float* bias  = (const float*)d_in[2];
    const float* left  = (const float*)d_in[3];
    const float* right = (const float*)d_in[4];
    const float* sbasis= (const float*)d_in[5];
    const float* w1    = (const float*)d_in[6];
    const float* b1    = (const float*)d_in[7];
    const float* rcw   = (const float*)d_in[8];
    const float* rcb   = (const float*)d_in[9];
    const float* rgw   = (const float*)d_in[10];
    const float* rgb   = (const float*)d_in[11];
    const float* scw   = (const float*)d_in[12];
    const float* scb   = (const float*)d_in[13];
    const float* sgw   = (const float*)d_in[14];
    const float* sgb   = (const float*)d_in[15];
    float* out = (float*)d_out;
    (void)in_sizes; (void)n_in; (void)out_size; (void)ws_size;

    char* wsp = (char*)d_ws;
    size_t off = 0;
    auto take = [&](size_t bytes) -> char* {
        char* p = wsp + off;
        off = (off + bytes + 255) & ~(size_t)255;
        return p;
    };
    u16*   xb   = (u16*)  take((size_t)ROWS*INF*2);     // 32 MB
    u16*   Wb   = (u16*)  take((size_t)OUTF*INF*2);     // 8 MB
    u16*   Utb  = (u16*)  take((size_t)128*1024*2);
    u16*   Yb   = (u16*)  take((size_t)ROWS*128*2);     // 4 MB
    u16*   Qb   = (u16*)  take((size_t)ROWS*128*2);     // 4 MB
    u16*   Vb   = (u16*)  take((size_t)OUTF*128*2);     // 1 MB
    u16*   Ptb  = (u16*)  take((size_t)32*128*128*2);   // 1 MB
    float* Uf   = (float*)take((size_t)1024*128*4);
    float* Gf   = (float*)take((size_t)128*128*4);
    float* ps   = (float*)take((size_t)32*8*1024*4);
    float* pq   = (float*)take((size_t)32*8*1024*4);
    float* rc   = (float*)take(32*8*4);
    float* sc   = (float*)take(32*8*4);
    float* rg   = (float*)take(32*4);
    float* sg   = (float*)take(32*4);
    float* nrm  = (float*)take(8*4);
    float* scl  = (float*)take((size_t)32*4096*4);

    k_cvt   <<<dim3(4096),   dim3(256), 0, stream>>>(Wsh, Wb, OUTF*INF/4);
    k_stats <<<dim3(8,32),   dim3(256), 0, stream>>>(x, xb, ps, pq);
    k_buildU<<<dim3(512),    dim3(256), 0, stream>>>(left, right, Uf, Utb);
    k_gram  <<<dim3(64),     dim3(256), 0, stream>>>(Uf, Gf);
    k_norms <<<dim3(8),      dim3(64),  0, stream>>>(Gf, nrm);
    k_ctrl  <<<dim3(32),     dim3(256), 0, stream>>>(x, ps, pq, w1, b1, rcw, rcb,
                                                     rgw, rgb, scw, scb, sgw, sgb,
                                                     rc, rg, sc, sg);
    k_solve <<<dim3(32),     dim3(1024), 0, stream>>>(Gf, rc, nrm, rg, Ptb);
    k_scale <<<dim3(512),    dim3(256), 0, stream>>>(sc, sbasis, sg, scl);
    // Y = x U            (16384 x 128, K=1024)
    k_gemm_bt<<<dim3(1,128,1), dim3(256), 0, stream>>>(xb, Utb, Yb, ROWS, 128, 1024, 0L, 0L, 0L);
    // Q = Y P  per batch (512 x 128, K=128)
    k_gemm_bt<<<dim3(1,4,32),  dim3(256), 0, stream>>>(Yb, Ptb, Qb, 512, 128, 128,
                                                       (long)512*128, (long)128*128, (long)512*128);
    // V = Wsh U          (4096 x 128, K=1024)
    k_gemm_bt<<<dim3(1,32,1),  dim3(256), 0, stream>>>(Wb, Utb, Vb, OUTF, 128, 1024, 0L, 0L, 0L);
    // out = (x W^T + Q V^T + bias) * scale
    k_main  <<<dim3(32,128), dim3(256), 0, stream>>>(xb, Wb, Qb, Vb, bias, scl, out);
}

// Round 3
// 828.292 us; speedup vs baseline: 2.7277x; 1.6191x over previous
//
#include <hip/hip_runtime.h>
#include <hip/hip_bf16.h>

typedef unsigned short u16;
typedef short short8 __attribute__((ext_vector_type(8)));
typedef float f32x4 __attribute__((ext_vector_type(4)));

#define B_    32
#define N_    512
#define INF   1024
#define OUTF  4096
#define ROWS  16384     // B_*N_
#define HID_  128
#define CTRL  3072

__device__ __forceinline__ u16 f2bf(float f) {
    union { float fv; unsigned int u; } v; v.fv = f;
    unsigned int x = v.u;
    unsigned int r = (x + 0x7fffu + ((x >> 16) & 1u)) >> 16;
    return (u16)r;
}

// async global->LDS, 16B per lane. lds ptr must be the WAVE-UNIFORM base;
// lane l deposits at base + l*16.
__device__ __forceinline__ void gll16(const void* g, const void* l) {
    __builtin_amdgcn_global_load_lds(
        (__attribute__((address_space(1))) void*)(unsigned long long)g,
        (__attribute__((address_space(3))) void*)(unsigned int)(unsigned long long)l,
        16, 0, 0);
}

// by-VALUE 16-way select (cndmask chain; no address taken -> no scratch demotion)
__device__ __forceinline__ float sel16(float4 a, float4 b, float4 c4, float4 d, int m) {
    float v = a.x;
    v = (m == 1) ? a.y : v;  v = (m == 2) ? a.z : v;  v = (m == 3) ? a.w : v;
    v = (m == 4) ? b.x : v;  v = (m == 5) ? b.y : v;  v = (m == 6) ? b.z : v;  v = (m == 7) ? b.w : v;
    v = (m == 8) ? c4.x : v; v = (m == 9) ? c4.y : v; v = (m == 10) ? c4.z : v; v = (m == 11) ? c4.w : v;
    v = (m == 12) ? d.x : v; v = (m == 13) ? d.y : v; v = (m == 14) ? d.z : v; v = (m == 15) ? d.w : v;
    return v;
}

// ---------------- stats (partial sums) + x->bf16 convert -------------------
__global__ __launch_bounds__(256) void k_stats(const float* __restrict__ x,
        u16* __restrict__ xb, float* __restrict__ ps, float* __restrict__ pq) {
    int b = blockIdx.y, bn = blockIdx.x, t = threadIdx.x;
    const float4* xp = (const float4*)(x + (size_t)b*(N_*INF) + (size_t)bn*64*INF);
    size_t obase = ((size_t)b*(N_*INF) + (size_t)bn*64*INF) >> 2;
    float sx=0, sy=0, sz=0, sw=0, qx=0, qy=0, qz=0, qw=0;
    for (int n = 0; n < 64; ++n) {
        float4 v = xp[n*256 + t];
        sx += v.x; sy += v.y; sz += v.z; sw += v.w;
        qx += v.x*v.x; qy += v.y*v.y; qz += v.z*v.z; qw += v.w*v.w;
        ushort4 o; o.x = f2bf(v.x); o.y = f2bf(v.y); o.z = f2bf(v.z); o.w = f2bf(v.w);
        ((ushort4*)xb)[obase + n*256 + t] = o;
    }
    int base = (b*8 + bn)*256 + t;
    float4 s4; s4.x=sx; s4.y=sy; s4.z=sz; s4.w=sw;
    float4 q4; q4.x=qx; q4.y=qy; q4.z=qz; q4.w=qw;
    ((float4*)ps)[base] = s4;
    ((float4*)pq)[base] = q4;
}

// ---------------- control MLP: coalesced wave-per-row GEMV -----------------
__global__ __launch_bounds__(256) void k_ctrl(const float* __restrict__ x,
    const float* __restrict__ ps, const float* __restrict__ pq,
    const float* __restrict__ w1, const float* __restrict__ b1,
    const float* __restrict__ rcw, const float* __restrict__ rcb,
    const float* __restrict__ rgw, const float* __restrict__ rgb,
    const float* __restrict__ scw, const float* __restrict__ scb,
    const float* __restrict__ sgw, const float* __restrict__ sgb,
    float* __restrict__ rc, float* __restrict__ rg,
    float* __restrict__ sc, float* __restrict__ sg)
{
    __shared__ float zs[CTRL];
    __shared__ float hs[HID_];
    int b = blockIdx.x, t = threadIdx.x;
    for (int d = t; d < 1024; d += 256) {
        float ssum = 0.f, qsum = 0.f;
        for (int j = 0; j < 8; ++j) {
            ssum += ps[(b*8 + j)*1024 + d];
            qsum += pq[(b*8 + j)*1024 + d];
        }
        float mean = ssum * (1.0f/512.0f);
        float var  = qsum * (1.0f/512.0f) - mean*mean;
        zs[d]        = x[(size_t)b*(N_*INF) + d];
        zs[1024 + d] = mean;
        zs[2048 + d] = var;
    }
    __syncthreads();
    int w = t >> 6, l = t & 63;
    const float4* zp = (const float4*)zs;
    for (int i = w; i < HID_; i += 4) {
        const float4* wr = (const float4*)(w1 + (size_t)i*CTRL);
        float acc = 0.f;
        #pragma unroll
        for (int c = 0; c < 12; ++c) {
            float4 a4 = wr[l + 64*c];
            float4 z4 = zp[l + 64*c];
            acc += a4.x*z4.x + a4.y*z4.y + a4.z*z4.z + a4.w*z4.w;
        }
        #pragma unroll
        for (int o2 = 32; o2 > 0; o2 >>= 1) acc += __shfl_down(acc, o2, 64);
        if (l == 0) {
            float u = acc + b1[i];
            hs[i] = 0.5f*u*(1.0f + tanhf(0.7978845608028654f*(u + 0.044715f*u*u*u)));
        }
    }
    __syncthreads();
    if (t < 8) {
        float a = rcb[t]; const float* wv = rcw + t*HID_;
        for (int i = 0; i < HID_; ++i) a += hs[i]*wv[i];
        rc[b*8 + t] = a;
    } else if (t < 16) {
        int j = t - 8;
        float a = scb[j]; const float* wv = scw + j*HID_;
        for (int i = 0; i < HID_; ++i) a += hs[i]*wv[i];
        sc[b*8 + j] = a;
    } else if (t == 16) {
        float a = rgb[0] - 4.0f;
        for (int i = 0; i < HID_; ++i) a += hs[i]*rgw[i];
        rg[b] = 1.0f/(1.0f + expf(-a));
    } else if (t == 17) {
        float a = sgb[0] - 2.5f;
        for (int i = 0; i < HID_; ++i) a += hs[i]*sgw[i];
        sg[b] = 1.0f/(1.0f + expf(-a));
    }
}

// ---------------- basis norms from Gram blocks of G ------------------------
__global__ __launch_bounds__(64) void k_norms(const float* __restrict__ G,
        float* __restrict__ norms) {
    int k = blockIdx.x, t = threadIdx.x;
    int i = t >> 3, j = t & 7;
    float A  = G[(16*k + i)*128     + 16*k + j];
    float C  = G[(16*k + 8 + i)*128 + 16*k + 8 + j];
    float D  = G[(16*k + 8 + i)*128 + 16*k + j];
    float Dj = G[(16*k + 8 + j)*128 + 16*k + i];
    float term = A*C - D*Dj;
    #pragma unroll
    for (int o2 = 32; o2 > 0; o2 >>= 1) term += __shfl_down(term, o2, 64);
    if (t == 0) norms[k] = fmaxf(sqrtf(fmaxf(2.0f*term, 0.0f)), 1e-6f);
}

// ---------------- build U (1024x128 f32) and U^T (bf16, 128x1024) ----------
__global__ __launch_bounds__(256) void k_buildU(const float* __restrict__ L,
        const float* __restrict__ R, float* __restrict__ U, u16* __restrict__ Utb) {
    int idx = blockIdx.x*256 + threadIdx.x;
    int d = idx >> 7, col = idx & 127;
    int k = col >> 4, rr = col & 15;
    float v = (rr < 8) ? L[((size_t)k<<13) + (d<<3) + rr]
                       : R[((size_t)k<<13) + (d<<3) + (rr-8)];
    U[idx] = v;
    Utb[col*1024 + d] = f2bf(v);
}

// ---------------- G = U^T U (128x128) --------------------------------------
__global__ __launch_bounds__(256) void k_gram(const float* __restrict__ U,
        float* __restrict__ G) {
    int e = blockIdx.x*256 + threadIdx.x;
    int i = e >> 7, j = e & 127;
    float a = 0.f;
    for (int d = 0; d < 1024; ++d) a += U[d*128 + i]*U[d*128 + j];
    G[e] = a;
}

// ---------------- per-batch 128x128 inversion, register-resident GJ --------
// Thread (r=t&127, s=t>>7) owns A[r][16s..16s+15] in NAMED float4s o0..o3
// (no address taken anywhere -> stays in VGPRs). LDS: double-buffered pivot
// row (+1 marker at pivot col) and pivot column. 1 barrier per column.
__global__ __launch_bounds__(1024, 4) void k_solve(const float* __restrict__ G,
    const float* __restrict__ rc, const float* __restrict__ norms,
    const float* __restrict__ rg, u16* __restrict__ Ptb)
{
    __shared__ float smem[16384];          // 64KB; first 512 floats = pivot bufs
    float* prow = smem;                    // [2][128]
    float* pcol = smem + 256;              // [2][128]
    int b = blockIdx.x, t = threadIdx.x;
    int r = t & 127, s = t >> 7;           // s is wave-uniform
    int kr = r >> 4, rr = r & 15;
    float a_r = rc[b*8 + kr] / norms[kr];
    int partner = (rr < 8) ? (kr*16 + 8 + rr) : (kr*16 + rr - 8);
    float sg0 = (rr < 8) ? -0.5f*a_r : 0.5f*a_r;
    float4 o0, o1, o2, o3;
    {
        const float4* Gp = (const float4*)(G + (size_t)partner*128 + 16*s);
        float4 g0 = Gp[0], g1 = Gp[1], g2 = Gp[2], g3 = Gp[3];
        int base = 16*s;
        o0.x = sg0*g0.x + ((r == base+0 ) ? 1.f : 0.f);
        o0.y = sg0*g0.y + ((r == base+1 ) ? 1.f : 0.f);
        o0.z = sg0*g0.z + ((r == base+2 ) ? 1.f : 0.f);
        o0.w = sg0*g0.w + ((r == base+3 ) ? 1.f : 0.f);
        o1.x = sg0*g1.x + ((r == base+4 ) ? 1.f : 0.f);
        o1.y = sg0*g1.y + ((r == base+5 ) ? 1.f : 0.f);
        o1.z = sg0*g1.z + ((r == base+6 ) ? 1.f : 0.f);
        o1.w = sg0*g1.w + ((r == base+7 ) ? 1.f : 0.f);
        o2.x = sg0*g2.x + ((r == base+8 ) ? 1.f : 0.f);
        o2.y = sg0*g2.y + ((r == base+9 ) ? 1.f : 0.f);
        o2.z = sg0*g2.z + ((r == base+10) ? 1.f : 0.f);
        o2.w = sg0*g2.w + ((r == base+11) ? 1.f : 0.f);
        o3.x = sg0*g3.x + ((r == base+12) ? 1.f : 0.f);
        o3.y = sg0*g3.y + ((r == base+13) ? 1.f : 0.f);
        o3.z = sg0*g3.z + ((r == base+14) ? 1.f : 0.f);
        o3.w = sg0*g3.w + ((r == base+15) ? 1.f : 0.f);
    }
    // pivots for column 0 -> buffer 0 (marker +1 at element j==0)
    if (r == 0) {
        float4 v0 = o0, v1 = o1, v2 = o2, v3 = o3;
        if (s == 0) v0.x += 1.0f;
        *(float4*)(prow + 16*s +  0) = v0;
        *(float4*)(prow + 16*s +  4) = v1;
        *(float4*)(prow + 16*s +  8) = v2;
        *(float4*)(prow + 16*s + 12) = v3;
    }
    if (s == 0) pcol[r] = o0.x;
    __syncthreads();
    for (int c = 0; c < 128; ++c) {
        int buf = c & 1, nb = buf ^ 1;
        float fr = pcol[buf*128 + r];
        const float4* prp = (const float4*)(prow + buf*128 + 16*s);
        float4 p0 = prp[0], p1 = prp[1], p2 = prp[2], p3 = prp[3];
        float pv = prow[buf*128 + c] - 1.0f;   // un-marked pivot value
        float invp = 1.0f / pv;
        if (r == c) {
            int base = 16*s;
            o0.x = (base+0  == c) ? invp : o0.x*invp;
            o0.y = (base+1  == c) ? invp : o0.y*invp;
            o0.z = (base+2  == c) ? invp : o0.z*invp;
            o0.w = (base+3  == c) ? invp : o0.w*invp;
            o1.x = (base+4  == c) ? invp : o1.x*invp;
            o1.y = (base+5  == c) ? invp : o1.y*invp;
            o1.z = (base+6  == c) ? invp : o1.z*invp;
            o1.w = (base+7  == c) ? invp : o1.w*invp;
            o2.x = (base+8  == c) ? invp : o2.x*invp;
            o2.y = (base+9  == c) ? invp : o2.y*invp;
            o2.z = (base+10 == c) ? invp : o2.z*invp;
            o2.w = (base+11 == c) ? invp : o2.w*invp;
            o3.x = (base+12 == c) ? invp : o3.x*invp;
            o3.y = (base+13 == c) ? invp : o3.y*invp;
            o3.z = (base+14 == c) ? invp : o3.z*invp;
            o3.w = (base+15 == c) ? invp : o3.w*invp;
        } else {
            float fi = fr * invp;
            o0.x -= fi*p0.x; o0.y -= fi*p0.y; o0.z -= fi*p0.z; o0.w -= fi*p0.w;
            o1.x -= fi*p1.x; o1.y -= fi*p1.y; o1.z -= fi*p1.z; o1.w -= fi*p1.w;
            o2.x -= fi*p2.x; o2.y -= fi*p2.y; o2.z -= fi*p2.z; o2.w -= fi*p2.w;
            o3.x -= fi*p3.x; o3.y -= fi*p3.y; o3.z -= fi*p3.z; o3.w -= fi*p3.w;
        }
        int cn = c + 1;
        if (cn < 128) {
            if (r == cn) {
                float4 v0 = o0, v1 = o1, v2 = o2, v3 = o3;
                int base = 16*s;
                v0.x += (base+0  == cn) ? 1.f : 0.f;
                v0.y += (base+1  == cn) ? 1.f : 0.f;
                v0.z += (base+2  == cn) ? 1.f : 0.f;
                v0.w += (base+3  == cn) ? 1.f : 0.f;
                v1.x += (base+4  == cn) ? 1.f : 0.f;
                v1.y += (base+5  == cn) ? 1.f : 0.f;
                v1.z += (base+6  == cn) ? 1.f : 0.f;
                v1.w += (base+7  == cn) ? 1.f : 0.f;
                v2.x += (base+8  == cn) ? 1.f : 0.f;
                v2.y += (base+9  == cn) ? 1.f : 0.f;
                v2.z += (base+10 == cn) ? 1.f : 0.f;
                v2.w += (base+11 == cn) ? 1.f : 0.f;
                v3.x += (base+12 == cn) ? 1.f : 0.f;
                v3.y += (base+13 == cn) ? 1.f : 0.f;
                v3.z += (base+14 == cn) ? 1.f : 0.f;
                v3.w += (base+15 == cn) ? 1.f : 0.f;
                *(float4*)(prow + nb*128 + 16*s +  0) = v0;
                *(float4*)(prow + nb*128 + 16*s +  4) = v1;
                *(float4*)(prow + nb*128 + 16*s +  8) = v2;
                *(float4*)(prow + nb*128 + 16*s + 12) = v3;
            }
            if (s == (cn >> 4)) pcol[nb*128 + r] = sel16(o0, o1, o2, o3, cn & 15);
        }
        __syncthreads();
    }
    // epilogue: ms = g * (M*S)[r][16s..16s+15]; Pt[16s+m][r] = ms[m]
    float as_ = rc[b*8 + s] / norms[s];
    float gg = rg[b];
    float na = -gg * as_, pa = gg * as_;
    smem[(16*s +  0)*128 + r] = na*o2.x;
    smem[(16*s +  1)*128 + r] = na*o2.y;
    smem[(16*s +  2)*128 + r] = na*o2.z;
    smem[(16*s +  3)*128 + r] = na*o2.w;
    smem[(16*s +  4)*128 + r] = na*o3.x;
    smem[(16*s +  5)*128 + r] = na*o3.y;
    smem[(16*s +  6)*128 + r] = na*o3.z;
    smem[(16*s +  7)*128 + r] = na*o3.w;
    smem[(16*s +  8)*128 + r] = pa*o0.x;
    smem[(16*s +  9)*128 + r] = pa*o0.y;
    smem[(16*s + 10)*128 + r] = pa*o0.z;
    smem[(16*s + 11)*128 + r] = pa*o0.w;
    smem[(16*s + 12)*128 + r] = pa*o1.x;
    smem[(16*s + 13)*128 + r] = pa*o1.y;
    smem[(16*s + 14)*128 + r] = pa*o1.z;
    smem[(16*s + 15)*128 + r] = pa*o1.w;
    __syncthreads();
    int r2 = t >> 3, s2 = t & 7;
    const float4* rp = (const float4*)(smem + r2*128 + 16*s2);
    float4 v0 = rp[0], v1 = rp[1], v2 = rp[2], v3 = rp[3];
    uint4 w0, w1;
    w0.x = f2bf(v0.x) | ((unsigned)f2bf(v0.y) << 16);
    w0.y = f2bf(v0.z) | ((unsigned)f2bf(v0.w) << 16);
    w0.z = f2bf(v1.x) | ((unsigned)f2bf(v1.y) << 16);
    w0.w = f2bf(v1.z) | ((unsigned)f2bf(v1.w) << 16);
    w1.x = f2bf(v2.x) | ((unsigned)f2bf(v2.y) << 16);
    w1.y = f2bf(v2.z) | ((unsigned)f2bf(v2.w) << 16);
    w1.z = f2bf(v3.x) | ((unsigned)f2bf(v3.y) << 16);
    w1.w = f2bf(v3.z) | ((unsigned)f2bf(v3.w) << 16);
    uint4* dst = (uint4*)(Ptb + ((size_t)(b*128 + r2))*128 + 16*s2);
    dst[0] = w0; dst[1] = w1;
}

// ---------------- output scale: 1 + sg*tanh(sc @ scale_basis) --------------
__global__ __launch_bounds__(256) void k_scale(const float* __restrict__ sc,
    const float* __restrict__ sbasis, const float* __restrict__ sg,
    float* __restrict__ scl) {
    int idx = blockIdx.x*256 + threadIdx.x;
    int b = idx >> 12, o = idx & 4095;
    float a = 0.f;
    #pragma unroll
    for (int k = 0; k < 8; ++k) a += sc[b*8 + k]*sbasis[(k<<12) + o];
    scl[idx] = 1.0f + sg[b]*tanhf(a);
}

// ---------------- f32 -> bf16 bulk convert ---------------------------------
__global__ __launch_bounds__(256) void k_cvt(const float* __restrict__ in,
        u16* __restrict__ out, int n4) {
    int i = blockIdx.x*256 + threadIdx.x;
    if (i < n4) {
        float4 v = ((const float4*)in)[i];
        ushort4 o; o.x=f2bf(v.x); o.y=f2bf(v.y); o.z=f2bf(v.z); o.w=f2bf(v.w);
        ((ushort4*)out)[i] = o;
    }
}

// ---------------- generic bf16 MFMA GEMM: C[m,n] = sum_k A[m,k]*Bt[n,k] ----
__global__ __launch_bounds__(256) void k_gemm_bt(const u16* __restrict__ A,
    const u16* __restrict__ Bt, u16* __restrict__ C,
    int M, int N, int K, long sA_, long sB_, long sC_)
{
    A  += (size_t)blockIdx.z * sA_;
    Bt += (size_t)blockIdx.z * sB_;
    C  += (size_t)blockIdx.z * sC_;
    int bm = blockIdx.y, bn = blockIdx.x;
    __shared__ __align__(16) u16 sA[128*64];
    __shared__ __align__(16) u16 sB[128*64];
    int tid = threadIdx.x;
    int wave = tid >> 6, lane = tid & 63;
    int wbase = tid & ~63;
    int wm = wave >> 1, wn = wave & 1;
    int quad = lane >> 4, l16 = lane & 15;
    f32x4 acc[4][4];
    #pragma unroll
    for (int i = 0; i < 4; ++i)
        #pragma unroll
        for (int j = 0; j < 4; ++j) { f32x4 z4 = {0.f,0.f,0.f,0.f}; acc[i][j] = z4; }
    int nk = K >> 6;
    for (int kt = 0; kt < nk; ++kt) {
        __syncthreads();
        #pragma unroll
        for (int q2 = 0; q2 < 4; ++q2) {
            int c = q2*256 + tid, row = c >> 3, kc = c & 7;
            gll16(A  + (size_t)(bm*128 + row)*K + kt*64 + kc*8, sA + (size_t)(q2*256 + wbase)*8);
            gll16(Bt + (size_t)(bn*128 + row)*K + kt*64 + kc*8, sB + (size_t)(q2*256 + wbase)*8);
        }
        __syncthreads();
        #pragma unroll
        for (int ks = 0; ks < 2; ++ks) {
            short8 af[4], bfv[4];
            #pragma unroll
            for (int i = 0; i < 4; ++i)
                af[i] = *(const short8*)(sA + (wm*64 + i*16 + l16)*64 + ks*32 + quad*8);
            #pragma unroll
            for (int j = 0; j < 4; ++j)
                bfv[j] = *(const short8*)(sB + (wn*64 + j*16 + l16)*64 + ks*32 + quad*8);
            #pragma unroll
            for (int i = 0; i < 4; ++i)
                #pragma unroll
                for (int j = 0; j < 4; ++j)
                    acc[i][j] = __builtin_amdgcn_mfma_f32_16x16x32_bf16(af[i], bfv[j], acc[i][j], 0, 0, 0);
        }
    }
    #pragma unroll
    for (int i = 0; i < 4; ++i)
        #pragma unroll
        for (int j = 0; j < 4; ++j) {
            int gcol = bn*128 + wn*64 + j*16 + l16;
            #pragma unroll
            for (int r = 0; r < 4; ++r) {
                int grow = bm*128 + wm*64 + i*16 + quad*4 + r;
                C[(size_t)grow*N + gcol] = f2bf(acc[i][j][r]);
            }
        }
}

// ---------------- main fused GEMM: out = (x W^T + Q V^T + bias) * scale ----
__global__ __launch_bounds__(256) void k_main(const u16* __restrict__ xb,
    const u16* __restrict__ Wb, const u16* __restrict__ Qb,
    const u16* __restrict__ Vb, const float* __restrict__ bias,
    const float* __restrict__ scale, float* __restrict__ out)
{
    int bm = blockIdx.y, bn = blockIdx.x;
    __shared__ __align__(16) u16 sA[128*64];
    __shared__ __align__(16) u16 sB[128*64];
    int tid = threadIdx.x;
    int wave = tid >> 6, lane = tid & 63;
    int wbase = tid & ~63;
    int wm = wave >> 1, wn = wave & 1;
    int quad = lane >> 4, l16 = lane & 15;
    f32x4 acc[4][4];
    #pragma unroll
    for (int i = 0; i < 4; ++i)
        #pragma unroll
        for (int j = 0; j < 4; ++j) { f32x4 z4 = {0.f,0.f,0.f,0.f}; acc[i][j] = z4; }
    for (int kt = 0; kt < 18; ++kt) {
        __syncthreads();
        if (kt < 16) {
            #pragma unroll
            for (int q2 = 0; q2 < 4; ++q2) {
                int c = q2*256 + tid, row = c >> 3, kc = c & 7;
                gll16(xb + (size_t)(bm*128 + row)*1024 + kt*64 + kc*8, sA + (size_t)(q2*256 + wbase)*8);
                gll16(Wb + (size_t)(bn*128 + row)*1024 + kt*64 + kc*8, sB + (size_t)(q2*256 + wbase)*8);
            }
        } else {
            int k0 = (kt - 16)*64;
            #pragma unroll
            for (int q2 = 0; q2 < 4; ++q2) {
                int c = q2*256 + tid, row = c >> 3, kc = c & 7;
                gll16(Qb + (size_t)(bm*128 + row)*128 + k0 + kc*8, sA + (size_t)(q2*256 + wbase)*8);
                gll16(Vb + (size_t)(bn*128 + row)*128 + k0 + kc*8, sB + (size_t)(q2*256 + wbase)*8);
            }
        }
        __syncthreads();
        #pragma unroll
        for (int ks = 0; ks < 2; ++ks) {
            short8 af[4], bfv[4];
            #pragma unroll
            for (int i = 0; i < 4; ++i)
                af[i] = *(const short8*)(sA + (wm*64 + i*16 + l16)*64 + ks*32 + quad*8);
            #pragma unroll
            for (int j = 0; j < 4; ++j)
                bfv[j] = *(const short8*)(sB + (wn*64 + j*16 + l16)*64 + ks*32 + quad*8);
            #pragma unroll
            for (int i = 0; i < 4; ++i)
                #pragma unroll
                for (int j = 0; j < 4; ++j)
                    acc[i][j] = __builtin_amdgcn_mfma_f32_16x16x32_bf16(af[i], bfv[j], acc[i][j], 0, 0, 0);
        }
    }
    const float* scrow = scale + (bm >> 2)*4096;  // 128-row blocks never cross batch
    #pragma unroll
    for (int i = 0; i < 4; ++i)
        #pragma unroll
        for (int j = 0; j < 4; ++j) {
            int gcol = bn*128 + wn*64 + j*16 + l16;
            float bc = bias[gcol];
            float sv = scrow[gcol];
            #pragma unroll
            for (int r = 0; r < 4; ++r) {
                int grow = bm*128 + wm*64 + i*16 + quad*4 + r;
                out[(size_t)grow*4096 + gcol] = (acc[i][j][r] + bc) * sv;
            }
        }
}

extern "C" void kernel_launch(void* const* d_in, const int* in_sizes, int n_in,
                              void* d_out, int out_size, void* d_ws, size_t ws_size,
                              hipStream_t stream)
{
    const float* x     = (const float*)d_in[0];
    const float* Wsh   = (const float*)d_in[1];
    const float* bias  = (const float*)d_in[2];
    const float* left  = (const float*)d_in[3];
    const float* right = (const float*)d_in[4];
    const float* sbasis= (const float*)d_in[5];
    const float* w1    = (const float*)d_in[6];
    const float* b1    = (const float*)d_in[7];
    const float* rcw   = (const float*)d_in[8];
    const float* rcb   = (const float*)d_in[9];
    const float* rgw   = (const float*)d_in[10];
    const float* rgb   = (const float*)d_in[11];
    const float* scw   = (const float*)d_in[12];
    const float* scb   = (const float*)d_in[13];
    const float* sgw   = (const float*)d_in[14];
    const float* sgb   = (const float*)d_in[15];
    float* out = (float*)d_out;
    (void)in_sizes; (void)n_in; (void)out_size; (void)ws_size;

    char* wsp = (char*)d_ws;
    size_t off = 0;
    auto take = [&](size_t bytes) -> char* {
        char* p = wsp + off;
        off = (off + bytes + 255) & ~(size_t)255;
        return p;
    };
    u16*   xb   = (u16*)  take((size_t)ROWS*INF*2);     // 32 MB
    u16*   Wb   = (u16*)  take((size_t)OUTF*INF*2);     // 8 MB
    u16*   Utb  = (u16*)  take((size_t)128*1024*2);
    u16*   Yb   = (u16*)  take((size_t)ROWS*128*2);     // 4 MB
    u16*   Qb   = (u16*)  take((size_t)ROWS*128*2);     // 4 MB
    u16*   Vb   = (u16*)  take((size_t)OUTF*128*2);     // 1 MB
    u16*   Ptb  = (u16*)  take((size_t)32*128*128*2);   // 1 MB
    float* Uf   = (float*)take((size_t)1024*128*4);
    float* Gf   = (float*)take((size_t)128*128*4);
    float* ps   = (float*)take((size_t)32*8*1024*4);
    float* pq   = (float*)take((size_t)32*8*1024*4);
    float* rc   = (float*)take(32*8*4);
    float* sc   = (float*)take(32*8*4);
    float* rg   = (float*)take(32*4);
    float* sg   = (float*)take(32*4);
    float* nrm  = (float*)take(8*4);
    float* scl  = (float*)take((size_t)32*4096*4);

    k_cvt   <<<dim3(4096),   dim3(256), 0, stream>>>(Wsh, Wb, OUTF*INF/4);
    k_stats <<<dim3(8,32),   dim3(256), 0, stream>>>(x, xb, ps, pq);
    k_buildU<<<dim3(512),    dim3(256), 0, stream>>>(left, right, Uf, Utb);
    k_gram  <<<dim3(64),     dim3(256), 0, stream>>>(Uf, Gf);
    k_norms <<<dim3(8),      dim3(64),  0, stream>>>(Gf, nrm);
    k_ctrl  <<<dim3(32),     dim3(256), 0, stream>>>(x, ps, pq, w1, b1, rcw, rcb,
                                                     rgw, rgb, scw, scb, sgw, sgb,
                                                     rc, rg, sc, sg);
    k_solve <<<dim3(32),     dim3(1024), 0, stream>>>(Gf, rc, nrm, rg, Ptb);
    k_scale <<<dim3(512),    dim3(256), 0, stream>>>(sc, sbasis, sg, scl);
    // Y = x U            (16384 x 128, K=1024)
    k_gemm_bt<<<dim3(1,128,1), dim3(256), 0, stream>>>(xb, Utb, Yb, ROWS, 128, 1024, 0L, 0L, 0L);
    // Q = Y P  per batch (512 x 128, K=128)
    k_gemm_bt<<<dim3(1,4,32),  dim3(256), 0, stream>>>(Yb, Ptb, Qb, 512, 128, 128,
                                                       (long)512*128, (long)128*128, (long)512*128);
    // V = Wsh U          (4096 x 128, K=1024)
    k_gemm_bt<<<dim3(1,32,1),  dim3(256), 0, stream>>>(Wb, Utb, Vb, OUTF, 128, 1024, 0L, 0L, 0L);
    // out = (x W^T + Q V^T + bias) * scale
    k_main  <<<dim3(32,128), dim3(256), 0, stream>>>(xb, Wb, Qb, Vb, bias, scl, out);
}